// Round 13
// baseline (20023.634 us; speedup 1.0000x reference)
//
#include <hip/hip_runtime.h>
#include <hip/hip_bf16.h>
#include <math.h>

#define TT 256
#define BB 128
#define SS 256
#define HH 512
#define EE 512
#define NBLK 128
#define NTHR 512
#define BH (BB * HH)

typedef __attribute__((ext_vector_type(4))) float f32x4;
typedef __attribute__((ext_vector_type(2))) float f32x2;
typedef __attribute__((ext_vector_type(8))) short s16x8;
typedef unsigned long long u64;

__device__ __forceinline__ float b2f(short v) {
    union { unsigned u; float f; } c;
    c.u = ((unsigned)(unsigned short)v) << 16;
    return c.f;
}
__device__ __forceinline__ short f2b(float f) {
    union { float f; unsigned u; } c; c.f = f;
    unsigned u = c.u;
    unsigned r = (u + 0x7fffu + ((u >> 16) & 1u)) >> 16;
    return (short)r;
}
__device__ __forceinline__ float sigm(float x) { return 1.f / (1.f + __expf(-x)); }

__device__ __forceinline__ unsigned short f2fp8x2(float x, float y) {
    return (unsigned short)(__builtin_amdgcn_cvt_pk_fp8_f32(x, y, 0, false) & 0xffff);
}

// agent-scope (LLC-coherent, cache-bypassing) exchange primitives
__device__ __forceinline__ u64 aldq(const void* p) {
    return __hip_atomic_load((const u64*)p, __ATOMIC_RELAXED, __HIP_MEMORY_SCOPE_AGENT);
}
__device__ __forceinline__ void ast2(short* p, short v) {
    __hip_atomic_store(p, v, __ATOMIC_RELAXED, __HIP_MEMORY_SCOPE_AGENT);
}
__device__ __forceinline__ s16x8 ald16(const void* p) {
    s16x8 r;
    asm volatile("global_load_dwordx4 %0, %1, off sc0 sc1" : "=v"(r) : "v"(p) : "memory");
    return r;
}

// LDS-only barrier: does NOT drain vmcnt
__device__ __forceinline__ void lbar() {
    asm volatile("s_waitcnt lgkmcnt(0)" ::: "memory");
    __builtin_amdgcn_s_barrier();
}

// ---------------- prep kernels ----------------

__global__ void k_pack2(const float* __restrict__ Wa, int ka, const float* __restrict__ Wb, int kb,
                        short* __restrict__ dst, int n) {
    const int K = ka + kb;
    for (int i = blockIdx.x * blockDim.x + threadIdx.x; i < n; i += gridDim.x * blockDim.x) {
        int g = i / K, k = i - g * K;
        float v = (k < ka) ? Wa[(size_t)g * ka + k] : Wb[(size_t)g * kb + (k - ka)];
        dst[i] = f2b(v);
    }
}

__global__ void k_bias(const float* __restrict__ a, const float* __restrict__ b, float* __restrict__ o,
                       const float* __restrict__ a2, const float* __restrict__ b2, float* __restrict__ o2) {
    int i = blockIdx.x * blockDim.x + threadIdx.x;
    if (i < 2048) { o[i] = a[i] + b[i]; o2[i] = a2[i] + b2[i]; }
}

__global__ void k_emb(const int* __restrict__ tok, const float* __restrict__ emb, short* __restrict__ Ebf) {
    const int n = TT * BB * EE;
    for (int i = blockIdx.x * blockDim.x + threadIdx.x; i < n; i += gridDim.x * blockDim.x) {
        int tb = i >> 9, k = i & 511;
        int t = tok[tb];
        Ebf[i] = f2b(emb[(size_t)t * EE + k]);
    }
}

// ctx [S,B,H] f32 -> fp8 [B,S,H]
__global__ void k_ctx8(const float* __restrict__ ctx, unsigned char* __restrict__ c8) {
    const int n2 = BB * SS * (HH / 2);
    for (int i = blockIdx.x * blockDim.x + threadIdx.x; i < n2; i += gridDim.x * blockDim.x) {
        int h2 = i & 255, rest = i >> 8;
        int s = rest & 255, b = rest >> 8;
        int h = h2 * 2;
        const float* src = ctx + ((size_t)s * BB + b) * HH + h;
        *reinterpret_cast<unsigned short*>(c8 + ((size_t)b * SS + s) * HH + h) = f2fp8x2(src[0], src[1]);
    }
}

__global__ void k_state(const float* __restrict__ h0in, const float* __restrict__ iout,
                        short* __restrict__ h0x, short* __restrict__ h1x, short* __restrict__ outx) {
    int i = blockIdx.x * blockDim.x + threadIdx.x;
    if (i < BH) {
        h0x[i] = f2b(h0in[i]);
        h1x[i] = f2b(h0in[BH + i]);
        outx[i] = f2b(iout[i]);
    }
}

// ---------------- persistent cooperative kernel ----------------

struct P {
    const short* Ebf;
    const float* c0in;
    const unsigned char* ctxb8;   // [b][s][h] fp8 raw ctx — scores AND PV
    const short* Winb;            // bf16 [n][512]
    const short* Woutb;           // bf16 [j][1024]
    const short* W0cat;
    const short* W1cat;
    const float* bias0;
    const float* bias1;
    short* h0x;
    short* h1x;
    short* outx;
    float* dout;
    unsigned* flags;              // one flag per 64B line: flags[blk*16]
};

#define MFMA16(a, b, c) __builtin_amdgcn_mfma_f32_16x16x32_bf16((a), (b), (c), 0, 0, 0)
#define MFMA8(a, b, c) __builtin_amdgcn_mfma_f32_16x16x32_fp8_fp8((a), (b), (c), 0, 0, 0)

#define CSTRIDE 536   // fp8 ctx tile row stride in bytes (8B-aligned, 16-row conflict-free)

__device__ __forceinline__ s16x8 ldsfrag(const short* base, int stride, int row, int col8) {
    return *reinterpret_cast<const s16x8*>(base + row * stride + ((col8 ^ (row & 7)) << 3));
}

__device__ __forceinline__ void issue8(const short* __restrict__ src, int tid, int khalf, s16x8* q) {
#pragma unroll
    for (int c = 0; c < 8; ++c) {
        const int chunk = c * 512 + tid;
        const int row = chunk >> 5, col8 = chunk & 31;
        q[c] = ald16(src + row * HH + khalf * 256 + col8 * 8);
    }
}
template <int N>
__device__ __forceinline__ void write8n(short* __restrict__ stg, int tid, const s16x8* q) {
    asm volatile("s_waitcnt vmcnt(%0)" ::"i"(N) : "memory");
#pragma unroll
    for (int c = 0; c < 8; ++c) {
        const int chunk = c * 512 + tid;
        const int row = chunk >> 5, col8 = chunk & 31;
        *reinterpret_cast<s16x8*>(stg + row * 256 + ((col8 ^ (row & 7)) << 3)) = q[c];
    }
}

__device__ __forceinline__ f32x4 seg8(const short* stgp, const short* Ws, int wstride, int wbase,
                                      int mrow, int wrow, int kq, f32x4 acc) {
#pragma unroll
    for (int seg = 0; seg < 8; ++seg)
        acc = MFMA16(ldsfrag(stgp, 256, mrow, seg * 4 + kq),
                     ldsfrag(Ws, wstride, wrow, wbase + seg * 4 + kq), acc);
    return acc;
}

// full grid barrier, contention-fixed (one flag per 64B line)
__device__ __forceinline__ void gbar(unsigned* flags, unsigned target) {
    asm volatile("s_waitcnt vmcnt(0)" ::: "memory");
    __syncthreads();
    if (threadIdx.x == 0)
        __hip_atomic_store(&flags[blockIdx.x * 16], target, __ATOMIC_RELAXED, __HIP_MEMORY_SCOPE_AGENT);
    if (threadIdx.x < NBLK) {
        while (__hip_atomic_load(&flags[threadIdx.x * 16], __ATOMIC_RELAXED, __HIP_MEMORY_SCOPE_AGENT) < target)
            __builtin_amdgcn_s_sleep(8);
    }
    __syncthreads();
}

__global__ void __launch_bounds__(NTHR, 1) coop_k(P p) {
    extern __shared__ __align__(16) char smem[];
    short* W0s = (short*)smem;                 // 16 x 1536 sw (49152B)
    short* W1s = W0s + 16 * 1536;              // 16 x 1024 sw (32768B)
    short* stg = W1s + 16 * 1024;              // 68608B region: A/B stage (64KB) / C ctx tile [128][536] / PV partials
    char* smallc = (char*)stg + 128 * CSTRIDE;
    float* bias0s = (float*)smallc;            // 16
    float* bias1s = bias0s + 16;               // 16
    float* red = bias1s + 16;                  // 16
    float* scv = red + 16;                     // 256
    float* aU = scv + 256;                     // 256
    short* catb = (short*)(aU + 256);          // 1024 shorts: [wc | h1] bf16
    unsigned char* q8b = (unsigned char*)(catb + 1024);  // 512 bytes fp8 q

    const int tid = threadIdx.x;
    const int blk = blockIdx.x;
    const int l = tid & 63;
    const int w = tid >> 6;
    const int lrow = l & 15;
    const int mrow = w * 16 + lrow;
    const int kq = l >> 4;
    const size_t OFF_HF = (size_t)TT * BH;
    const size_t OFF_CF = OFF_HF + 2 * (size_t)BH;
    const size_t OFF_AT = OFF_CF + 2 * (size_t)BH;
    const f32x4 fz = {0.f, 0.f, 0.f, 0.f};

    // --- prologue ---
    for (int idx = tid; idx < 16 * 192; idx += NTHR) {
        int row = idx / 192, col8 = idx % 192;
        int g = (row & 3) * 512 + blk * 4 + (row >> 2);
        *reinterpret_cast<s16x8*>(W0s + row * 1536 + ((col8 ^ (row & 7)) << 3)) =
            *reinterpret_cast<const s16x8*>(p.W0cat + (size_t)g * 1536 + col8 * 8);
    }
    for (int idx = tid; idx < 16 * 128; idx += NTHR) {
        int row = idx / 128, col8 = idx % 128;
        int g = (row & 3) * 512 + blk * 4 + (row >> 2);
        *reinterpret_cast<s16x8*>(W1s + row * 1024 + ((col8 ^ (row & 7)) << 3)) =
            *reinterpret_cast<const s16x8*>(p.W1cat + (size_t)g * 1024 + col8 * 8);
    }
    if (tid < 16) {
        int g = (tid & 3) * 512 + blk * 4 + (tid >> 2);
        bias0s[tid] = p.bias0[g];
        bias1s[tid] = p.bias1[g];
    }
    __syncthreads();

    const int bA = tid >> 2;
    const int jA = blk * 4 + (tid & 3);
    float c0reg = p.c0in[bA * HH + jA];
    float c1reg = p.c0in[BH + bA * HH + jA];
    unsigned ep = 0;
    s16x8 qa[8], qb[8], qc[8], qd[8];

    for (int t = 0; t < TT; ++t) {
        const size_t pB = (size_t)(t & 1) * BH;
        const size_t pN = (size_t)((t & 1) ^ 1) * BH;

        // ================= Phase A: layer-0 gates + cell =================
        {
            issue8(p.outx + pB, tid, 0, qa);
            issue8(p.outx + pB, tid, 1, qb);
            f32x4 aE = fz, aO = fz, aH = fz;
            {
                const short* erow = p.Ebf + ((size_t)t * BB + mrow) * EE + kq * 8;
#pragma unroll
                for (int seg = 0; seg < 16; ++seg) {
                    s16x8 afr = *reinterpret_cast<const s16x8*>(erow + seg * 32);
                    aE = MFMA16(afr, ldsfrag(W0s, 1536, lrow, seg * 4 + kq), aE);
                }
            }
            write8n<8>(stg, tid, qa);
            issue8(p.h0x + pB, tid, 0, qc);
            lbar();
            aO = seg8(stg, W0s, 1536, 64, mrow, lrow, kq, aO);
            lbar();
            write8n<8>(stg, tid, qb);
            issue8(p.h0x + pB, tid, 1, qd);
            lbar();
            aO = seg8(stg, W0s, 1536, 96, mrow, lrow, kq, aO);
            lbar();
            write8n<8>(stg, tid, qc);
            lbar();
            aH = seg8(stg, W0s, 1536, 128, mrow, lrow, kq, aH);
            lbar();
            write8n<0>(stg, tid, qd);
            lbar();
            aH = seg8(stg, W0s, 1536, 160, mrow, lrow, kq, aH);

            f32x4 acc = aE + aO + aH;
            lbar();
            float* scr = (float*)stg + w * 272;
#pragma unroll
            for (int r = 0; r < 4; ++r) scr[lrow * 17 + kq * 4 + r] = acc[r];
            const int bloc = l >> 2;
            const int n0 = (l & 3) * 4;
            float gi = scr[(n0 + 0) * 17 + bloc] + bias0s[n0 + 0];
            float gf = scr[(n0 + 1) * 17 + bloc] + bias0s[n0 + 1];
            float gg = scr[(n0 + 2) * 17 + bloc] + bias0s[n0 + 2];
            float go = scr[(n0 + 3) * 17 + bloc] + bias0s[n0 + 3];
            float cn = sigm(gf) * c0reg + sigm(gi) * tanhf(gg);
            float hn = sigm(go) * tanhf(cn);
            c0reg = cn;
            ast2(&p.h0x[pN + bA * HH + jA], f2b(hn));
            if (t == TT - 1) {
                p.dout[OFF_HF + bA * HH + jA] = hn;
                p.dout[OFF_CF + bA * HH + jA] = cn;
            }
        }
        gbar(p.flags, ++ep);

        // ================= Phase B: layer-1 gates + cell =================
        {
            issue8(p.h0x + pN, tid, 0, qa);
            issue8(p.h0x + pN, tid, 1, qb);
            f32x4 b0 = fz, b1 = fz;
            write8n<8>(stg, tid, qa);
            issue8(p.h1x + pB, tid, 0, qc);
            lbar();
            b0 = seg8(stg, W1s, 1024, 0, mrow, lrow, kq, b0);
            lbar();
            write8n<8>(stg, tid, qb);
            issue8(p.h1x + pB, tid, 1, qd);
            lbar();
            b0 = seg8(stg, W1s, 1024, 32, mrow, lrow, kq, b0);
            lbar();
            write8n<8>(stg, tid, qc);
            lbar();
            b1 = seg8(stg, W1s, 1024, 64, mrow, lrow, kq, b1);
            lbar();
            write8n<0>(stg, tid, qd);
            lbar();
            b1 = seg8(stg, W1s, 1024, 96, mrow, lrow, kq, b1);

            f32x4 acc = b0 + b1;
            lbar();
            float* scr = (float*)stg + w * 272;
#pragma unroll
            for (int r = 0; r < 4; ++r) scr[lrow * 17 + kq * 4 + r] = acc[r];
            const int bloc = l >> 2;
            const int n0 = (l & 3) * 4;
            float gi = scr[(n0 + 0) * 17 + bloc] + bias1s[n0 + 0];
            float gf = scr[(n0 + 1) * 17 + bloc] + bias1s[n0 + 1];
            float gg = scr[(n0 + 2) * 17 + bloc] + bias1s[n0 + 2];
            float go = scr[(n0 + 3) * 17 + bloc] + bias1s[n0 + 3];
            float cn = sigm(gf) * c1reg + sigm(gi) * tanhf(gg);
            float hn = sigm(go) * tanhf(cn);
            c1reg = cn;
            ast2(&p.h1x[pN + bA * HH + jA], f2b(hn));
            if (t == TT - 1) {
                p.dout[OFF_HF + BH + bA * HH + jA] = hn;
                p.dout[OFF_CF + BH + bA * HH + jA] = cn;
            }
        }
        gbar(p.flags, ++ep);

        // ===== Phase C: attention + output for batch row b = blk =====
        // Both passes read the SAME L2-resident fp8 ctx slice (128KB/block).
        {
            unsigned char* ctile = (unsigned char*)stg;   // [128][CSTRIDE] staging (scores)
            float* pF = (float*)stg;                       // PV partials [4][512] (after scores)
            const unsigned char* cgb = p.ctxb8 + (size_t)blk * SS * HH;
            // h1 -> catb[512..1024) bf16
            if (tid < 128) {
                u64 v = aldq(p.h1x + pN + blk * HH + tid * 4);
                *reinterpret_cast<u64*>(catb + 512 + tid * 4) = v;
            }
            lbar();
            // q-GEMV: q[n] = Winb[n,:] . h1  (bf16 MFMA, A = h1 broadcast)
#pragma unroll
            for (int i = 0; i < 4; ++i) {
                const int j0 = (w * 4 + i) * 16;
                f32x4 acc = fz;
#pragma unroll
                for (int kc = 0; kc < 16; ++kc) {
                    const int k0 = kc * 32;
                    s16x8 av = *reinterpret_cast<const s16x8*>(catb + 512 + k0 + kq * 8);
                    s16x8 bv = *reinterpret_cast<const s16x8*>(p.Winb + (size_t)(j0 + lrow) * 512 + k0 + kq * 8);
                    acc = MFMA16(av, bv, acc);
                }
                if (l < 16)
                    q8b[j0 + l] = (unsigned char)(__builtin_amdgcn_cvt_pk_fp8_f32(acc[0], 0.f, 0, false) & 0xff);
            }
            // scores over two s-halves: stage 64KB to LDS (cached loads), fp8 MFMA
#pragma unroll
            for (int half = 0; half < 2; ++half) {
                lbar();   // q8 ready / previous half's reads done
                {
                    const int srow = tid >> 2, seg = tid & 3;
                    const unsigned char* gsrc = cgb + (size_t)(half * 128 + srow) * HH + seg * 128;
                    char* drow = (char*)ctile + (size_t)srow * CSTRIDE + seg * 128;
#pragma unroll
                    for (int j = 0; j < 8; ++j) {
                        union { float4 f; u64 q[2]; } cc;
                        cc.f = *reinterpret_cast<const float4*>(gsrc + j * 16);
                        u64* d = reinterpret_cast<u64*>(drow + j * 16);
                        d[0] = cc.q[0];
                        d[1] = cc.q[1];
                    }
                }
                lbar();
                {
                    const u64* q8q = (const u64*)q8b;
                    f32x4 acc = fz;
#pragma unroll
                    for (int kc = 0; kc < 16; ++kc) {
                        const int k0 = kc * 32;
                        long long av = (long long)q8q[(k0 >> 3) + kq];
                        long long bv = (long long)*reinterpret_cast<const u64*>(
                            (const char*)ctile + (size_t)(w * 16 + lrow) * CSTRIDE + k0 + kq * 8);
                        acc = MFMA8(av, bv, acc);
                    }
                    if (l < 16) scv[half * 128 + w * 16 + l] = acc[0];
                }
            }
            lbar();
            // softmax over 256
            float sc = -1e30f, e = 0.f;
            if (tid < 256) sc = scv[tid];
            float mx = sc;
#pragma unroll
            for (int off = 32; off; off >>= 1) mx = fmaxf(mx, __shfl_xor(mx, off));
            if (l == 0 && tid < 256) red[w] = mx;
            lbar();
            const float M = fmaxf(fmaxf(red[0], red[1]), fmaxf(red[2], red[3]));
            if (tid < 256) { e = __expf(sc - M); aU[tid] = e; }
            float se = e;
#pragma unroll
            for (int off = 32; off; off >>= 1) se += __shfl_xor(se, off);
            if (l == 0 && tid < 256) red[8 + w] = se;
            lbar();
            const float inv = 1.f / (red[8] + red[9] + red[10] + red[11]);
            if (t == TT - 1 && tid < 256) p.dout[OFF_AT + blk * SS + tid] = aU[tid] * inv;
            // PV directly from global (L2-hit dwords): thread owns 4 h, quarter of s
            {
                const int hd = tid & 127;
                const int sg = tid >> 7;
                float pv0 = 0.f, pv1 = 0.f, pv2 = 0.f, pv3 = 0.f;
#pragma unroll 8
                for (int s = sg * 64; s < sg * 64 + 64; ++s) {
                    const float av = aU[s];
                    unsigned dv = *reinterpret_cast<const unsigned*>(cgb + (size_t)s * HH + hd * 4);
                    f32x2 lo = __builtin_amdgcn_cvt_pk_f32_fp8(dv, false);
                    f32x2 hi = __builtin_amdgcn_cvt_pk_f32_fp8(dv, true);
                    pv0 += av * lo[0];
                    pv1 += av * lo[1];
                    pv2 += av * hi[0];
                    pv3 += av * hi[1];
                }
                lbar();   // ctile reads done; reuse stg as pF
                float4 vv = {pv0, pv1, pv2, pv3};
                *reinterpret_cast<float4*>(pF + sg * 512 + hd * 4) = vv;
            }
            lbar();
            // wc = (sum of 4 partials) * inv -> catb[0..512) bf16
            {
                float wc = (pF[tid] + pF[512 + tid] + pF[1024 + tid] + pF[1536 + tid]) * inv;
                catb[tid] = f2b(wc);
            }
            lbar();
            // out = tanh([wc|h1] @ Wout^T): bf16 MFMA, K=1024, B = Woutb rows (L2-resident)
#pragma unroll
            for (int i = 0; i < 4; ++i) {
                const int j0 = (w * 4 + i) * 16;
                f32x4 acc = fz;
#pragma unroll
                for (int kc = 0; kc < 32; ++kc) {
                    const int k0 = kc * 32;
                    s16x8 av = *reinterpret_cast<const s16x8*>(catb + k0 + kq * 8);
                    s16x8 bv = *reinterpret_cast<const s16x8*>(p.Woutb + (size_t)(j0 + lrow) * 1024 + k0 + kq * 8);
                    acc = MFMA16(av, bv, acc);
                }
                if (l < 16) {
                    const int j = j0 + l;
                    float tv = tanhf(acc[0]);
                    __builtin_nontemporal_store(tv, &p.dout[(size_t)t * BH + blk * HH + j]);
                    ast2(&p.outx[pN + blk * HH + j], f2b(tv));
                }
            }
        }
        gbar(p.flags, ++ep);
    }
}

// ---------------- host ----------------

extern "C" void kernel_launch(void* const* d_in, const int* in_sizes, int n_in,
                              void* d_out, int out_size, void* d_ws, size_t ws_size,
                              hipStream_t stream) {
    const int* tokens = (const int*)d_in[0];
    const float* h0in = (const float*)d_in[1];
    const float* c0in = (const float*)d_in[2];
    const float* ctx = (const float*)d_in[3];
    const float* iout = (const float*)d_in[4];
    const float* emb = (const float*)d_in[5];
    const float* Wih0 = (const float*)d_in[6];
    const float* bih0 = (const float*)d_in[7];
    const float* Whh0 = (const float*)d_in[8];
    const float* bhh0 = (const float*)d_in[9];
    const float* Wih1 = (const float*)d_in[10];
    const float* bih1 = (const float*)d_in[11];
    const float* Whh1 = (const float*)d_in[12];
    const float* bhh1 = (const float*)d_in[13];
    const float* Win = (const float*)d_in[14];
    const float* Wout = (const float*)d_in[15];
    float* dout = (float*)d_out;

    char* pw = (char*)d_ws;
    auto take = [&](size_t bytes) { char* r = pw; pw += (bytes + 255) & ~(size_t)255; return r; };
    short* W0cat = (short*)take((size_t)2048 * 1536 * 2);
    short* W1cat = (short*)take((size_t)2048 * 1024 * 2);
    short* Winb  = (short*)take((size_t)512 * 512 * 2);
    short* Woutb = (short*)take((size_t)512 * 1024 * 2);
    float* bias0 = (float*)take(2048 * 4);
    float* bias1 = (float*)take(2048 * 4);
    short* Ebf   = (short*)take((size_t)TT * BB * EE * 2);
    unsigned char* ctxb8 = (unsigned char*)take((size_t)BB * SS * HH);
    short* h0x   = (short*)take((size_t)2 * BH * 2);
    short* h1x   = (short*)take((size_t)2 * BH * 2);
    short* outx  = (short*)take((size_t)2 * BH * 2);
    unsigned* flags = (unsigned*)take(NBLK * 64);

    k_pack2<<<2048, 256, 0, stream>>>(Wih0, 1024, Whh0, 512, W0cat, 2048 * 1536);
    k_pack2<<<2048, 256, 0, stream>>>(Wih1, 512, Whh1, 512, W1cat, 2048 * 1024);
    k_pack2<<<1024, 256, 0, stream>>>(Win, 512, Win, 0, Winb, 512 * 512);
    k_pack2<<<1024, 256, 0, stream>>>(Wout, 1024, Wout, 0, Woutb, 512 * 1024);
    k_bias<<<8, 256, 0, stream>>>(bih0, bhh0, bias0, bih1, bhh1, bias1);
    k_emb<<<4096, 256, 0, stream>>>(tokens, emb, Ebf);
    k_ctx8<<<4096, 256, 0, stream>>>(ctx, ctxb8);
    k_state<<<256, 256, 0, stream>>>(h0in, iout, h0x, h1x, outx);
    (void)hipMemsetAsync(flags, 0, NBLK * 64, stream);

    const unsigned smem_bytes = (16 * 1536 + 16 * 1024) * 2 + 128 * CSTRIDE + (16 + 16 + 16 + 256 + 256) * 4 + 1024 * 2 + 512;
    (void)hipFuncSetAttribute((const void*)coop_k, hipFuncAttributeMaxDynamicSharedMemorySize, (int)smem_bytes);

    P prm;
    prm.Ebf = Ebf; prm.c0in = c0in;
    prm.ctxb8 = ctxb8; prm.Winb = Winb; prm.Woutb = Woutb;
    prm.W0cat = W0cat; prm.W1cat = W1cat;
    prm.bias0 = bias0; prm.bias1 = bias1;
    prm.h0x = h0x; prm.h1x = h1x; prm.outx = outx;
    prm.dout = dout; prm.flags = flags;
    void* args[] = {&prm};
    (void)hipLaunchCooperativeKernel((void*)coop_k, dim3(NBLK), dim3(NTHR), args, smem_bytes, stream);
}

// Round 14
// 13914.832 us; speedup vs baseline: 1.4390x; 1.4390x over previous
//
#include <hip/hip_runtime.h>
#include <hip/hip_bf16.h>
#include <math.h>

#define TT 256
#define BB 128
#define SS 256
#define HH 512
#define EE 512
#define NBLK 128
#define NTHR 512
#define BH (BB * HH)

typedef __attribute__((ext_vector_type(4))) float f32x4;
typedef __attribute__((ext_vector_type(8))) short s16x8;
typedef unsigned long long u64;

__device__ __forceinline__ float b2f(short v) {
    union { unsigned u; float f; } c;
    c.u = ((unsigned)(unsigned short)v) << 16;
    return c.f;
}
__device__ __forceinline__ short f2b(float f) {
    union { float f; unsigned u; } c; c.f = f;
    unsigned u = c.u;
    unsigned r = (u + 0x7fffu + ((u >> 16) & 1u)) >> 16;
    return (short)r;
}
__device__ __forceinline__ float sigm(float x) { return 1.f / (1.f + __expf(-x)); }

__device__ __forceinline__ unsigned short f2fp8x2(float x, float y) {
    return (unsigned short)(__builtin_amdgcn_cvt_pk_fp8_f32(x, y, 0, false) & 0xffff);
}

// agent-scope (LLC-coherent, cache-bypassing) primitives — used ONLY where the
// address is reused across steps (outx 2-slot buffer, barrier flags).
__device__ __forceinline__ u64 aldq(const void* p) {
    return __hip_atomic_load((const u64*)p, __ATOMIC_RELAXED, __HIP_MEMORY_SCOPE_AGENT);
}
__device__ __forceinline__ void ast2(short* p, short v) {
    __hip_atomic_store(p, v, __ATOMIC_RELAXED, __HIP_MEMORY_SCOPE_AGENT);
}
__device__ __forceinline__ s16x8 ald16(const void* p) {   // uncached 16B
    s16x8 r;
    asm volatile("global_load_dwordx4 %0, %1, off sc0 sc1" : "=v"(r) : "v"(p) : "memory");
    return r;
}
__device__ __forceinline__ s16x8 ald16c(const void* p) {  // CACHED 16B (ring slots: first-touch-per-step => no stale-line hazard)
    s16x8 r;
    asm volatile("global_load_dwordx4 %0, %1, off" : "=v"(r) : "v"(p) : "memory");
    return r;
}

// LDS-only barrier: does NOT drain vmcnt
__device__ __forceinline__ void lbar() {
    asm volatile("s_waitcnt lgkmcnt(0)" ::: "memory");
    __builtin_amdgcn_s_barrier();
}

// ---------------- prep kernels ----------------

__global__ void k_pack2(const float* __restrict__ Wa, int ka, const float* __restrict__ Wb, int kb,
                        short* __restrict__ dst, int n) {
    const int K = ka + kb;
    for (int i = blockIdx.x * blockDim.x + threadIdx.x; i < n; i += gridDim.x * blockDim.x) {
        int g = i / K, k = i - g * K;
        float v = (k < ka) ? Wa[(size_t)g * ka + k] : Wb[(size_t)g * kb + (k - ka)];
        dst[i] = f2b(v);
    }
}

__global__ void k_bias(const float* __restrict__ a, const float* __restrict__ b, float* __restrict__ o,
                       const float* __restrict__ a2, const float* __restrict__ b2, float* __restrict__ o2) {
    int i = blockIdx.x * blockDim.x + threadIdx.x;
    if (i < 2048) { o[i] = a[i] + b[i]; o2[i] = a2[i] + b2[i]; }
}

// out8 = fp8( ctx[s,b,:] @ Wb[n,:]^T );  transpose=0: [(b,s), n];  transpose=1: [(b,n), s]
__global__ __launch_bounds__(512) void k_cvt8(const float* __restrict__ ctx, const short* __restrict__ Wb,
                                              int wstride, int transpose, unsigned char* __restrict__ out8) {
    const int tid = threadIdx.x, w = tid >> 6, l = tid & 63;
    const int m0 = blockIdx.y * 128, n0 = blockIdx.x * 64;
    const int kc8 = (l >> 4) * 8;
    const int m = m0 + w * 16 + (l & 15);
    const int b = m >> 8, s = m & 255;
    const float* arow = ctx + ((size_t)s * BB + b) * HH + kc8;
    f32x4 acc[4];
    const f32x4 zero = {0.f, 0.f, 0.f, 0.f};
#pragma unroll
    for (int j = 0; j < 4; ++j) acc[j] = zero;
#pragma unroll
    for (int kc = 0; kc < 16; ++kc) {
        const int k0 = kc * 32;
        float4 x0 = *reinterpret_cast<const float4*>(arow + k0);
        float4 x1 = *reinterpret_cast<const float4*>(arow + k0 + 4);
        s16x8 afr;
        afr[0] = f2b(x0.x); afr[1] = f2b(x0.y); afr[2] = f2b(x0.z); afr[3] = f2b(x0.w);
        afr[4] = f2b(x1.x); afr[5] = f2b(x1.y); afr[6] = f2b(x1.z); afr[7] = f2b(x1.w);
#pragma unroll
        for (int j = 0; j < 4; ++j) {
            s16x8 bfr = *reinterpret_cast<const s16x8*>(Wb + (size_t)(n0 + j * 16 + (l & 15)) * wstride + k0 + kc8);
            acc[j] = __builtin_amdgcn_mfma_f32_16x16x32_bf16(afr, bfr, acc[j], 0, 0, 0);
        }
    }
#pragma unroll
    for (int j = 0; j < 4; ++j)
#pragma unroll
        for (int r = 0; r < 4; ++r) {
            const int mm = m0 + w * 16 + (l >> 4) * 4 + r;
            const int nn = n0 + j * 16 + (l & 15);
            unsigned char v8 = (unsigned char)(__builtin_amdgcn_cvt_pk_fp8_f32(acc[j][r], 0.f, 0, false) & 0xff);
            if (transpose) {
                const int bb = mm >> 8, ss = mm & 255;
                out8[((size_t)bb * HH + nn) * SS + ss] = v8;
            } else {
                out8[(size_t)mm * HH + nn] = v8;
            }
        }
}

__global__ void k_state(const float* __restrict__ h0in, const float* __restrict__ iout,
                        short* __restrict__ h0r, short* __restrict__ h1r, short* __restrict__ outx) {
    int i = blockIdx.x * blockDim.x + threadIdx.x;
    if (i < BH) {
        h0r[i] = f2b(h0in[i]);          // ring slot 0
        h1r[i] = f2b(h0in[BH + i]);     // ring slot 0
        outx[i] = f2b(iout[i]);
    }
}

// ---------------- persistent cooperative kernel ----------------

struct P {
    const int* tokens;
    const float* emb;
    const float* c0in;
    const unsigned char* ctxW8;   // [(b,s), n] fp8: scores source
    const unsigned char* ctxO8T;  // [(b,h'), s] fp8: PV-in-output-space, transposed
    const short* Woutb;           // bf16 [j][1024]
    const short* W0cat;
    const short* W1cat;
    const float* bias0;
    const float* bias1;
    short* h0r;                   // ring [TT+1][BH]
    short* h1r;                   // ring [TT+1][BH]
    short* outx;                  // 2-slot uncached
    float* dout;
    unsigned* flags;              // one flag per 64B line
};

#define MFMA16(a, b, c) __builtin_amdgcn_mfma_f32_16x16x32_bf16((a), (b), (c), 0, 0, 0)
#define MFMA8(a, b, c) __builtin_amdgcn_mfma_f32_16x16x32_fp8_fp8((a), (b), (c), 0, 0, 0)

__device__ __forceinline__ s16x8 ldsfrag(const short* base, int stride, int row, int col8) {
    return *reinterpret_cast<const s16x8*>(base + row * stride + ((col8 ^ (row & 7)) << 3));
}

template <bool CACHED>
__device__ __forceinline__ void issue8(const short* __restrict__ src, int tid, int khalf, s16x8* q) {
#pragma unroll
    for (int c = 0; c < 8; ++c) {
        const int chunk = c * 512 + tid;
        const int row = chunk >> 5, col8 = chunk & 31;
        const short* a = src + row * HH + khalf * 256 + col8 * 8;
        q[c] = CACHED ? ald16c(a) : ald16(a);
    }
}
template <int N>
__device__ __forceinline__ void write8n(short* __restrict__ stg, int tid, const s16x8* q) {
    asm volatile("s_waitcnt vmcnt(%0)" ::"i"(N) : "memory");
#pragma unroll
    for (int c = 0; c < 8; ++c) {
        const int chunk = c * 512 + tid;
        const int row = chunk >> 5, col8 = chunk & 31;
        *reinterpret_cast<s16x8*>(stg + row * 256 + ((col8 ^ (row & 7)) << 3)) = q[c];
    }
}

__device__ __forceinline__ f32x4 seg8(const short* stgp, const short* Ws, int wstride, int wbase,
                                      int mrow, int wrow, int kq, f32x4 acc) {
#pragma unroll
    for (int seg = 0; seg < 8; ++seg)
        acc = MFMA16(ldsfrag(stgp, 256, mrow, seg * 4 + kq),
                     ldsfrag(Ws, wstride, wrow, wbase + seg * 4 + kq), acc);
    return acc;
}

// full grid barrier, contention-fixed (one flag per 64B line)
__device__ __forceinline__ void gbar(unsigned* flags, unsigned target) {
    asm volatile("s_waitcnt vmcnt(0)" ::: "memory");
    __syncthreads();
    if (threadIdx.x == 0)
        __hip_atomic_store(&flags[blockIdx.x * 16], target, __ATOMIC_RELAXED, __HIP_MEMORY_SCOPE_AGENT);
    if (threadIdx.x < NBLK) {
        while (__hip_atomic_load(&flags[threadIdx.x * 16], __ATOMIC_RELAXED, __HIP_MEMORY_SCOPE_AGENT) < target)
            __builtin_amdgcn_s_sleep(8);
    }
    __syncthreads();
}

__global__ void __launch_bounds__(NTHR, 1) coop_k(P p) {
    extern __shared__ __align__(16) char smem[];
    short* W0s = (short*)smem;            // 16 x 1536 sw
    short* W1s = W0s + 16 * 1536;         // 16 x 1024 sw
    short* stg = W1s + 16 * 1024;         // 128 x 256 sw stage / scratch
    float* smallf = (float*)(stg + 128 * 256);
    float* bias0s = smallf;               // 16
    float* bias1s = smallf + 16;          // 16
    float* red = smallf + 32;             // 16
    float* scv = smallf + 48;             // 256
    float* aU = smallf + 304;             // 256
    short* h1b = (short*)(smallf + 560);  // 512 bf16
    unsigned* h18u = (unsigned*)(smallf + 816);  // 512 fp8
    unsigned* a32 = (unsigned*)(smallf + 944);   // 256 fp8

    const int tid = threadIdx.x;
    const int blk = blockIdx.x;
    const int l = tid & 63;
    const int w = tid >> 6;
    const int lrow = l & 15;
    const int mrow = w * 16 + lrow;
    const int kq = l >> 4;
    const size_t OFF_HF = (size_t)TT * BH;
    const size_t OFF_CF = OFF_HF + 2 * (size_t)BH;
    const size_t OFF_AT = OFF_CF + 2 * (size_t)BH;
    const f32x4 fz = {0.f, 0.f, 0.f, 0.f};

    // --- prologue ---
    for (int idx = tid; idx < 16 * 192; idx += NTHR) {
        int row = idx / 192, col8 = idx % 192;
        int g = (row & 3) * 512 + blk * 4 + (row >> 2);
        *reinterpret_cast<s16x8*>(W0s + row * 1536 + ((col8 ^ (row & 7)) << 3)) =
            *reinterpret_cast<const s16x8*>(p.W0cat + (size_t)g * 1536 + col8 * 8);
    }
    for (int idx = tid; idx < 16 * 128; idx += NTHR) {
        int row = idx / 128, col8 = idx % 128;
        int g = (row & 3) * 512 + blk * 4 + (row >> 2);
        *reinterpret_cast<s16x8*>(W1s + row * 1024 + ((col8 ^ (row & 7)) << 3)) =
            *reinterpret_cast<const s16x8*>(p.W1cat + (size_t)g * 1024 + col8 * 8);
    }
    if (tid < 16) {
        int g = (tid & 3) * 512 + blk * 4 + (tid >> 2);
        bias0s[tid] = p.bias0[g];
        bias1s[tid] = p.bias1[g];
    }
    __syncthreads();

    const int bA = tid >> 2;
    const int jA = blk * 4 + (tid & 3);
    float c0reg = p.c0in[bA * HH + jA];
    float c1reg = p.c0in[BH + bA * HH + jA];
    unsigned ep = 0;
    s16x8 qa[8], qb[8], qc[8], qd[8];

    for (int t = 0; t < TT; ++t) {
        const size_t pB = (size_t)(t & 1) * BH;
        const size_t pN = (size_t)((t & 1) ^ 1) * BH;
        const short* h0old = p.h0r + (size_t)t * BH;        // ring slot t (fresh-written last step)
        short* h0new = p.h0r + (size_t)(t + 1) * BH;        // ring slot t+1
        const short* h1old = p.h1r + (size_t)t * BH;
        short* h1new = p.h1r + (size_t)(t + 1) * BH;

        // ================= Phase A: layer-0 gates + cell =================
        {
            issue8<false>(p.outx + pB, tid, 0, qa);         // out(t-1): 2-slot, must stay uncached
            issue8<false>(p.outx + pB, tid, 1, qb);
            f32x4 aE = fz, aO = fz, aH = fz;
            {
                const int tok = p.tokens[t * BB + mrow];
                const float* erow = p.emb + (size_t)tok * EE + kq * 8;
#pragma unroll
                for (int seg = 0; seg < 16; ++seg) {
                    float4 x0 = *reinterpret_cast<const float4*>(erow + seg * 32);
                    float4 x1 = *reinterpret_cast<const float4*>(erow + seg * 32 + 4);
                    s16x8 afr;
                    afr[0] = f2b(x0.x); afr[1] = f2b(x0.y); afr[2] = f2b(x0.z); afr[3] = f2b(x0.w);
                    afr[4] = f2b(x1.x); afr[5] = f2b(x1.y); afr[6] = f2b(x1.z); afr[7] = f2b(x1.w);
                    aE = MFMA16(afr, ldsfrag(W0s, 1536, lrow, seg * 4 + kq), aE);
                }
            }
            write8n<8>(stg, tid, qa);
            issue8<true>(h0old, tid, 0, qc);                // h0(t-1): ring, cached
            lbar();
            aO = seg8(stg, W0s, 1536, 64, mrow, lrow, kq, aO);
            lbar();
            write8n<8>(stg, tid, qb);
            issue8<true>(h0old, tid, 1, qd);
            lbar();
            aO = seg8(stg, W0s, 1536, 96, mrow, lrow, kq, aO);
            lbar();
            write8n<8>(stg, tid, qc);
            lbar();
            aH = seg8(stg, W0s, 1536, 128, mrow, lrow, kq, aH);
            lbar();
            write8n<0>(stg, tid, qd);
            lbar();
            aH = seg8(stg, W0s, 1536, 160, mrow, lrow, kq, aH);

            f32x4 acc = aE + aO + aH;
            lbar();
            float* scr = (float*)stg + w * 272;
#pragma unroll
            for (int r = 0; r < 4; ++r) scr[lrow * 17 + kq * 4 + r] = acc[r];
            const int bloc = l >> 2;
            const int n0 = (l & 3) * 4;
            float gi = scr[(n0 + 0) * 17 + bloc] + bias0s[n0 + 0];
            float gf = scr[(n0 + 1) * 17 + bloc] + bias0s[n0 + 1];
            float gg = scr[(n0 + 2) * 17 + bloc] + bias0s[n0 + 2];
            float go = scr[(n0 + 3) * 17 + bloc] + bias0s[n0 + 3];
            float cn = sigm(gf) * c0reg + sigm(gi) * tanhf(gg);
            float hn = sigm(go) * tanhf(cn);
            c0reg = cn;
            ast2(&h0new[bA * HH + jA], f2b(hn));
            if (t == TT - 1) {
                p.dout[OFF_HF + bA * HH + jA] = hn;
                p.dout[OFF_CF + bA * HH + jA] = cn;
            }
        }
        gbar(p.flags, ++ep);

        // ================= Phase B: layer-1 gates + cell =================
        {
            issue8<true>(h0new, tid, 0, qa);                // h0(t): ring, cached
            issue8<true>(h0new, tid, 1, qb);
            f32x4 b0 = fz, b1 = fz;
            write8n<8>(stg, tid, qa);
            issue8<true>(h1old, tid, 0, qc);                // h1(t-1): ring, cached
            lbar();
            b0 = seg8(stg, W1s, 1024, 0, mrow, lrow, kq, b0);
            lbar();
            write8n<8>(stg, tid, qb);
            issue8<true>(h1old, tid, 1, qd);
            lbar();
            b0 = seg8(stg, W1s, 1024, 32, mrow, lrow, kq, b0);
            lbar();
            write8n<8>(stg, tid, qc);
            lbar();
            b1 = seg8(stg, W1s, 1024, 64, mrow, lrow, kq, b1);
            lbar();
            write8n<0>(stg, tid, qd);
            lbar();
            b1 = seg8(stg, W1s, 1024, 96, mrow, lrow, kq, b1);

            f32x4 acc = b0 + b1;
            lbar();
            float* scr = (float*)stg + w * 272;
#pragma unroll
            for (int r = 0; r < 4; ++r) scr[lrow * 17 + kq * 4 + r] = acc[r];
            const int bloc = l >> 2;
            const int n0 = (l & 3) * 4;
            float gi = scr[(n0 + 0) * 17 + bloc] + bias1s[n0 + 0];
            float gf = scr[(n0 + 1) * 17 + bloc] + bias1s[n0 + 1];
            float gg = scr[(n0 + 2) * 17 + bloc] + bias1s[n0 + 2];
            float go = scr[(n0 + 3) * 17 + bloc] + bias1s[n0 + 3];
            float cn = sigm(gf) * c1reg + sigm(gi) * tanhf(gg);
            float hn = sigm(go) * tanhf(cn);
            c1reg = cn;
            ast2(&h1new[bA * HH + jA], f2b(hn));
            if (t == TT - 1) {
                p.dout[OFF_HF + BH + bA * HH + jA] = hn;
                p.dout[OFF_CF + BH + bA * HH + jA] = cn;
            }
        }
        gbar(p.flags, ++ep);

        // ===== Phase C: attention + fused output row for batch b = blk (all-MFMA) =====
        {
            float* pFh = (float*)stg;   // 512 floats: PV result in output space
            if (tid < 128) {
                union { u64 v; short s[4]; } c;
                c.v = *reinterpret_cast<const u64*>(h1new + blk * HH + tid * 4);  // ring: cached read safe
#pragma unroll
                for (int j = 0; j < 4; ++j) h1b[tid * 4 + j] = c.s[j];
                float f0 = b2f(c.s[0]), f1 = b2f(c.s[1]), f2 = b2f(c.s[2]), f3 = b2f(c.s[3]);
                unsigned lo = __builtin_amdgcn_cvt_pk_fp8_f32(f0, f1, 0, false) & 0xffffu;
                unsigned hi = __builtin_amdgcn_cvt_pk_fp8_f32(f2, f3, 0, false) & 0xffffu;
                h18u[tid] = lo | (hi << 16);
            }
            lbar();
            // scores via fp8 MFMA: B = ctxW8 rows (16 s/tile), A = h1 fp8 broadcast
            {
                const unsigned char* cwb = p.ctxW8 + (size_t)blk * SS * HH;
                const u64* h18q = (const u64*)h18u;
#pragma unroll
                for (int i = 0; i < 2; ++i) {
                    const int s0 = (w * 2 + i) * 16;
                    f32x4 acc = fz;
#pragma unroll
                    for (int kc = 0; kc < 16; ++kc) {
                        const int k0 = kc * 32;
                        long long av = (long long)h18q[(k0 >> 3) + kq];
                        long long bv = *reinterpret_cast<const long long*>(cwb + (size_t)(s0 + lrow) * HH + k0 + kq * 8);
                        acc = MFMA8(av, bv, acc);
                    }
                    if (l < 16) scv[s0 + l] = acc[0];
                }
            }
            lbar();
            // softmax over 256
            float sc = -1e30f, e = 0.f;
            if (tid < 256) sc = scv[tid];
            float mx = sc;
#pragma unroll
            for (int off = 32; off; off >>= 1) mx = fmaxf(mx, __shfl_xor(mx, off));
            if (l == 0 && tid < 256) red[w] = mx;
            lbar();
            const float M = fmaxf(fmaxf(red[0], red[1]), fmaxf(red[2], red[3]));
            if (tid < 256) { e = __expf(sc - M); aU[tid] = e; }
            float se = e;
#pragma unroll
            for (int off = 32; off; off >>= 1) se += __shfl_xor(se, off);
            if (l == 0 && tid < 256) red[8 + w] = se;
            lbar();
            const float inv = 1.f / (red[8] + red[9] + red[10] + red[11]);
            if (t == TT - 1 && tid < 256) p.dout[OFF_AT + blk * SS + tid] = aU[tid] * inv;
            if (tid < 64) {
                unsigned lo = __builtin_amdgcn_cvt_pk_fp8_f32(aU[tid * 4], aU[tid * 4 + 1], 0, false) & 0xffffu;
                unsigned hi = __builtin_amdgcn_cvt_pk_fp8_f32(aU[tid * 4 + 2], aU[tid * 4 + 3], 0, false) & 0xffffu;
                a32[tid] = lo | (hi << 16);
            }
            // combine GEMV via bf16 MFMA: g[j] = h1 . WoutR[j]
            f32x4 gacc[4];
#pragma unroll
            for (int i = 0; i < 4; ++i) {
                const int j0 = (w * 4 + i) * 16;
                f32x4 acc = fz;
#pragma unroll
                for (int kc = 0; kc < 16; ++kc) {
                    const int k0 = kc * 32;
                    s16x8 av = *reinterpret_cast<const s16x8*>(h1b + k0 + kq * 8);
                    s16x8 bv = *reinterpret_cast<const s16x8*>(p.Woutb + (size_t)(j0 + lrow) * 1024 + 512 + k0 + kq * 8);
                    acc = MFMA16(av, bv, acc);
                }
                gacc[i] = acc;
            }
            lbar();   // a32 visible
            // PV via fp8 MFMA over transposed ctxO8T
            {
                const unsigned char* cob = p.ctxO8T + (size_t)blk * HH * SS;
                const u64* a8q = (const u64*)a32;
#pragma unroll
                for (int i = 0; i < 4; ++i) {
                    const int h0 = (w * 4 + i) * 16;
                    f32x4 acc = fz;
#pragma unroll
                    for (int kc = 0; kc < 8; ++kc) {
                        const int k0 = kc * 32;
                        long long av = (long long)a8q[(k0 >> 3) + kq];
                        long long bv = *reinterpret_cast<const long long*>(cob + (size_t)(h0 + lrow) * SS + k0 + kq * 8);
                        acc = MFMA8(av, bv, acc);
                    }
                    if (l < 16) pFh[h0 + l] = acc[0];
                }
            }
            lbar();   // pFh visible
#pragma unroll
            for (int i = 0; i < 4; ++i) {
                if (l < 16) {
                    const int j = (w * 4 + i) * 16 + l;
                    float tv = tanhf(pFh[j] * inv + gacc[i][0]);
                    __builtin_nontemporal_store(tv, &p.dout[(size_t)t * BH + blk * HH + j]);
                    ast2(&p.outx[pN + blk * HH + j], f2b(tv));
                }
            }
        }
        gbar(p.flags, ++ep);
    }
}

// ---------------- host ----------------

extern "C" void kernel_launch(void* const* d_in, const int* in_sizes, int n_in,
                              void* d_out, int out_size, void* d_ws, size_t ws_size,
                              hipStream_t stream) {
    const int* tokens = (const int*)d_in[0];
    const float* h0in = (const float*)d_in[1];
    const float* c0in = (const float*)d_in[2];
    const float* ctx = (const float*)d_in[3];
    const float* iout = (const float*)d_in[4];
    const float* emb = (const float*)d_in[5];
    const float* Wih0 = (const float*)d_in[6];
    const float* bih0 = (const float*)d_in[7];
    const float* Whh0 = (const float*)d_in[8];
    const float* bhh0 = (const float*)d_in[9];
    const float* Wih1 = (const float*)d_in[10];
    const float* bih1 = (const float*)d_in[11];
    const float* Whh1 = (const float*)d_in[12];
    const float* bhh1 = (const float*)d_in[13];
    const float* Win = (const float*)d_in[14];
    const float* Wout = (const float*)d_in[15];
    float* dout = (float*)d_out;

    char* pw = (char*)d_ws;
    auto take = [&](size_t bytes) { char* r = pw; pw += (bytes + 255) & ~(size_t)255; return r; };
    short* W0cat = (short*)take((size_t)2048 * 1536 * 2);
    short* W1cat = (short*)take((size_t)2048 * 1024 * 2);
    short* Winb  = (short*)take((size_t)512 * 512 * 2);
    short* Woutb = (short*)take((size_t)512 * 1024 * 2);
    float* bias0 = (float*)take(2048 * 4);
    float* bias1 = (float*)take(2048 * 4);
    unsigned char* ctxW8 = (unsigned char*)take((size_t)BB * SS * HH);
    unsigned char* ctxO8T = (unsigned char*)take((size_t)BB * SS * HH);
    short* h0r   = (short*)take((size_t)(TT + 1) * BH * 2);   // ring
    short* h1r   = (short*)take((size_t)(TT + 1) * BH * 2);   // ring
    short* outx  = (short*)take((size_t)2 * BH * 2);
    unsigned* flags = (unsigned*)take(NBLK * 64);

    k_pack2<<<2048, 256, 0, stream>>>(Wih0, 1024, Whh0, 512, W0cat, 2048 * 1536);
    k_pack2<<<2048, 256, 0, stream>>>(Wih1, 512, Whh1, 512, W1cat, 2048 * 1024);
    k_pack2<<<1024, 256, 0, stream>>>(Win, 512, Win, 0, Winb, 512 * 512);
    k_pack2<<<1024, 256, 0, stream>>>(Wout, 1024, Wout, 0, Woutb, 512 * 1024);
    k_bias<<<8, 256, 0, stream>>>(bih0, bhh0, bias0, bih1, bhh1, bias1);
    k_state<<<256, 256, 0, stream>>>(h0in, iout, h0r, h1r, outx);
    k_cvt8<<<dim3(8, 256), 512, 0, stream>>>(ctx, Winb, 512, 0, ctxW8);
    k_cvt8<<<dim3(8, 256), 512, 0, stream>>>(ctx, Woutb, 1024, 1, ctxO8T);
    (void)hipMemsetAsync(flags, 0, NBLK * 64, stream);

    const unsigned smem_bytes = (16 * 1536 + 16 * 1024 + 128 * 256) * 2 + 1008 * 4;
    (void)hipFuncSetAttribute((const void*)coop_k, hipFuncAttributeMaxDynamicSharedMemorySize, (int)smem_bytes);

    P prm;
    prm.tokens = tokens; prm.emb = emb; prm.c0in = c0in;
    prm.ctxW8 = ctxW8; prm.ctxO8T = ctxO8T; prm.Woutb = Woutb;
    prm.W0cat = W0cat; prm.W1cat = W1cat;
    prm.bias0 = bias0; prm.bias1 = bias1;
    prm.h0r = h0r; prm.h1r = h1r; prm.outx = outx;
    prm.dout = dout; prm.flags = flags;
    void* args[] = {&prm};
    (void)hipLaunchCooperativeKernel((void*)coop_k, dim3(NBLK), dim3(NTHR), args, smem_bytes, stream);
}